// Round 5
// baseline (187.414 us; speedup 1.0000x reference)
//
#include <hip/hip_runtime.h>
#include <hip/hip_bf16.h>

#define NB 16
#define C 256
#define C4 64
#define HDIM 128
#define WDIM 128
#define HW 16384

typedef __bf16 bf16x8 __attribute__((ext_vector_type(8)));
typedef float f32x4 __attribute__((ext_vector_type(4)));

__device__ __forceinline__ unsigned short f2bf(float x) {
    union { __bf16 h; unsigned short u; } c;
    c.h = (__bf16)x;                       // v_cvt_pk_bf16_f32, RNE
    return c.u;
}
__device__ __forceinline__ float bf2f(unsigned short b) {
    union { float f; unsigned u; } a; a.u = ((unsigned)b) << 16; return a.f;
}

// ---------------------------------------------------------------------------
// K0: pack conv_w (64x256) and fuse_w (256x64) into MFMA A-fragment order,
// and compute fuse_b_eff[c] = fuse_b[c] + sum_o fuse_w[c][o]*dw_b[o].
// A-fragment (16x16x32): lane = (m&15) | (((k>>3)&3)<<4), e = k&7.
// frag index = (m>>4)*(K/32) + (k>>5). Each frag = 64 lanes * 8 bf16 = 1 KiB.
// ---------------------------------------------------------------------------
__global__ __launch_bounds__(256) void k0_pack(
    const float* __restrict__ conv_w, const float* __restrict__ fuse_w,
    const float* __restrict__ fuse_b, const float* __restrict__ dw_b,
    unsigned short* __restrict__ cwpk, unsigned short* __restrict__ fwpk,
    float* __restrict__ fbe)
{
    int tid = blockIdx.x * 256 + threadIdx.x;   // 0..16383
    {   // conv_w: M=64, K=256
        int m = tid >> 8, k = tid & 255;
        int frag = (m >> 4) * 8 + (k >> 5);
        int lane = (m & 15) | (((k >> 3) & 3) << 4);
        int e = k & 7;
        cwpk[(frag * 64 + lane) * 8 + e] = f2bf(conv_w[m * 256 + k]);
    }
    {   // fuse_w: M=256, K=64
        int m = tid >> 6, k = tid & 63;
        int frag = (m >> 4) * 2 + (k >> 5);
        int lane = (m & 15) | (((k >> 3) & 3) << 4);
        int e = k & 7;
        fwpk[(frag * 64 + lane) * 8 + e] = f2bf(fuse_w[m * 64 + k]);
    }
    if (tid < 256) {
        float s = fuse_b[tid];
        #pragma unroll
        for (int o = 0; o < 64; ++o) s += fuse_w[tid * 64 + o] * dw_b[o];
        fbe[tid] = s;
    }
}

// ---------------------------------------------------------------------------
// K1: f = conv1(x) + conv_b   (GEMM: M=64 o, N=pixels, K=256 c), f -> bf16 ws.
// Block: 64 pixels x 64 out-channels. 4 waves, wave w owns pixels [16w,16w+16).
// x loads nontemporal (streamed once) so f stays LLC-resident for K2/K3.
// ---------------------------------------------------------------------------
__global__ __launch_bounds__(256) void k1_conv(
    const float* __restrict__ x, const unsigned short* __restrict__ cwpk,
    const float* __restrict__ conv_b, unsigned short* __restrict__ f_ws)
{
    int tile = blockIdx.x;                // 4096 tiles
    int n = tile >> 8;
    int p0 = (tile & 255) * 64;
    int lane = threadIdx.x & 63, wv = threadIdx.x >> 6;
    int gq = lane >> 4;
    int prow = p0 + wv * 16 + (lane & 15);
    const float* xn = x + (size_t)n * C * HW;

    f32x4 acc[4] = {{0.f,0.f,0.f,0.f},{0.f,0.f,0.f,0.f},
                    {0.f,0.f,0.f,0.f},{0.f,0.f,0.f,0.f}};
    for (int kc = 0; kc < 8; ++kc) {
        int cb = kc * 32 + gq * 8;
        union { bf16x8 v; unsigned short u[8]; } b;
        #pragma unroll
        for (int e = 0; e < 8; ++e)
            b.u[e] = f2bf(__builtin_nontemporal_load(&xn[(size_t)(cb + e) * HW + prow]));
        #pragma unroll
        for (int m = 0; m < 4; ++m) {
            bf16x8 a = *reinterpret_cast<const bf16x8*>(cwpk + ((m * 8 + kc) * 64 + lane) * 8);
            acc[m] = __builtin_amdgcn_mfma_f32_16x16x32_bf16(a, b.v, acc[m], 0, 0, 0);
        }
    }
    unsigned short* fn = f_ws + (size_t)n * C4 * HW;
    #pragma unroll
    for (int m = 0; m < 4; ++m) {
        #pragma unroll
        for (int e = 0; e < 4; ++e) {
            int o = m * 16 + gq * 4 + e;               // D row = 4*(lane>>4)+reg
            fn[(size_t)o * HW + prow] = f2bf(acc[m][e] + conv_b[o]);
        }
    }
}

// ---------------------------------------------------------------------------
// K2: g[n,o,i,j] = mean of f over torch-adaptive bins.
// H=W=128, k=3: bins [0,43),[42,86),[85,128)  (row 42 & 85 in TWO bins).
// One block per (n,o) plane.
// ---------------------------------------------------------------------------
__global__ __launch_bounds__(256) void k2_pool(
    const unsigned short* __restrict__ f_ws, float* __restrict__ g_ws)
{
    int no = blockIdx.x;                                  // 0..1023
    const unsigned short* fp = f_ws + (size_t)no * HW;
    int tid = threadIdx.x;
    float s[9];
    #pragma unroll
    for (int k = 0; k < 9; ++k) s[k] = 0.f;

    for (int it = 0; it < 8; ++it) {
        int p = (it * 256 + tid) * 8;                     // 8 bf16 per iter
        int h = p >> 7, wbase = p & 127;
        union { uint4 q; unsigned short u[8]; } d;
        d.q = *reinterpret_cast<const uint4*>(fp + p);
        float cs0 = 0.f, cs1 = 0.f, cs2 = 0.f;            // per-col-bin sums
        #pragma unroll
        for (int z = 0; z < 8; ++z) {
            float v = bf2f(d.u[z]);
            int w = wbase + z;
            if (w < 43)            cs0 += v;
            if (w >= 42 && w < 86) cs1 += v;
            if (w >= 85)           cs2 += v;
        }
        if (h < 43)            { s[0] += cs0; s[1] += cs1; s[2] += cs2; }
        if (h >= 42 && h < 86) { s[3] += cs0; s[4] += cs1; s[5] += cs2; }
        if (h >= 85)           { s[6] += cs0; s[7] += cs1; s[8] += cs2; }
    }

    __shared__ float red[4][9];
    int lane = tid & 63, wv = tid >> 6;
    #pragma unroll
    for (int k = 0; k < 9; ++k) {
        float v = s[k];
        for (int off = 32; off > 0; off >>= 1) v += __shfl_down(v, off, 64);
        s[k] = v;
    }
    if (lane == 0) {
        #pragma unroll
        for (int k = 0; k < 9; ++k) red[wv][k] = s[k];
    }
    __syncthreads();
    if (tid < 9) {
        const int cnt[3] = {43, 44, 43};
        float tot = red[0][tid] + red[1][tid] + red[2][tid] + red[3][tid];
        int i = tid / 3, j = tid - 3 * i;
        g_ws[no * 9 + tid] = tot / (float)(cnt[i] * cnt[j]);
    }
}

// ---------------------------------------------------------------------------
// K3: y = depthwise3x3(f, g) ; out = fuse_w . y + fuse_b_eff
// Block: one (n, row h), full 128 cols, 512 threads (8 waves).
// Depthwise: thread -> (channel o, 16-px strip). f reads vectorized uint4 +
// 2 clamped scalars (no per-element exec-mask divergence). y staged bf16 in
// LDS (stride 136 -> 16B-aligned, ~2-way banks), then MFMA K=64 -> 256 ch.
// Wave wv owns (64 ch x 64 px) quadrant: chb=(wv&3)*64, pxb=(wv>>2)*64.
// ---------------------------------------------------------------------------
__global__ __launch_bounds__(512) void k3_dwfuse(
    const unsigned short* __restrict__ f_ws, const float* __restrict__ g_ws,
    const unsigned short* __restrict__ fwpk, const float* __restrict__ fbe,
    float* __restrict__ out)
{
    __shared__ unsigned short ylds[64][136];
    int blk = blockIdx.x;                 // 2048
    int n = blk >> 7;
    int h = blk & 127;
    int t = threadIdx.x;

    {   // depthwise: thread t -> channel o = t>>3, strip q = t&7 (16 px)
        int o = t >> 3, q = t & 7;
        int wb = q * 16;
        const unsigned short* fp = f_ws + (size_t)(n * 64 + o) * HW;
        const float* gp = g_ws + (n * 64 + o) * 9;
        float gv[9];
        #pragma unroll
        for (int k = 0; k < 9; ++k) gv[k] = gp[k];
        float y[16];
        #pragma unroll
        for (int i = 0; i < 16; ++i) y[i] = 0.f;
        #pragma unroll
        for (int dy = -1; dy <= 1; ++dy) {
            int hh = h + dy;
            if (hh < 0 || hh >= HDIM) continue;
            const unsigned short* row = fp + hh * WDIM;
            union { uint4 q4; unsigned short u[8]; } bA, bB;
            bA.q4 = *reinterpret_cast<const uint4*>(row + wb);
            bB.q4 = *reinterpret_cast<const uint4*>(row + wb + 8);
            float lft = bf2f(row[wb == 0 ? 0 : wb - 1]);
            if (wb == 0)   lft = 0.f;
            float rgt = bf2f(row[wb == 112 ? 127 : wb + 16]);
            if (wb == 112) rgt = 0.f;
            float rv[18];
            rv[0] = lft;
            #pragma unroll
            for (int z = 0; z < 8; ++z) rv[1 + z] = bf2f(bA.u[z]);
            #pragma unroll
            for (int z = 0; z < 8; ++z) rv[9 + z] = bf2f(bB.u[z]);
            rv[17] = rgt;
            float g0 = gv[(dy + 1) * 3], g1 = gv[(dy + 1) * 3 + 1], g2 = gv[(dy + 1) * 3 + 2];
            #pragma unroll
            for (int i = 0; i < 16; ++i)
                y[i] += g0 * rv[i] + g1 * rv[i + 1] + g2 * rv[i + 2];
        }
        union { uint4 q4[2]; unsigned short u[16]; } pk;
        #pragma unroll
        for (int i = 0; i < 16; ++i) pk.u[i] = f2bf(y[i]);
        *reinterpret_cast<uint4*>(&ylds[o][wb])     = pk.q4[0];
        *reinterpret_cast<uint4*>(&ylds[o][wb + 8]) = pk.q4[1];
    }
    __syncthreads();

    int lane = t & 63, wv = t >> 6, gq = lane >> 4;
    int chb = (wv & 3) * 64, pxb = (wv >> 2) * 64;
    f32x4 acc[4][4];
    #pragma unroll
    for (int a = 0; a < 4; ++a)
        #pragma unroll
        for (int b = 0; b < 4; ++b) acc[a][b] = (f32x4){0.f,0.f,0.f,0.f};

    #pragma unroll
    for (int kc = 0; kc < 2; ++kc) {
        bf16x8 bfr[4];
        #pragma unroll
        for (int pj = 0; pj < 4; ++pj) {
            union { bf16x8 v; unsigned short u[8]; } bb;
            #pragma unroll
            for (int e = 0; e < 8; ++e)
                bb.u[e] = ylds[kc * 32 + gq * 8 + e][pxb + pj * 16 + (lane & 15)];
            bfr[pj] = bb.v;
        }
        #pragma unroll
        for (int mc = 0; mc < 4; ++mc) {
            int mtile = (wv & 3) * 4 + mc;
            bf16x8 a = *reinterpret_cast<const bf16x8*>(
                fwpk + ((mtile * 2 + kc) * 64 + lane) * 8);
            #pragma unroll
            for (int pj = 0; pj < 4; ++pj)
                acc[mc][pj] = __builtin_amdgcn_mfma_f32_16x16x32_bf16(a, bfr[pj], acc[mc][pj], 0, 0, 0);
        }
    }

    size_t outbase = (size_t)n * C * HW + (size_t)h * WDIM;
    #pragma unroll
    for (int mc = 0; mc < 4; ++mc) {
        #pragma unroll
        for (int e = 0; e < 4; ++e) {
            int c = chb + mc * 16 + gq * 4 + e;
            float bias = fbe[c];
            #pragma unroll
            for (int pj = 0; pj < 4; ++pj) {
                int w = pxb + pj * 16 + (lane & 15);
                __builtin_nontemporal_store(acc[mc][pj][e] + bias,
                                            &out[outbase + (size_t)c * HW + w]);
            }
        }
    }
}

// ---------------------------------------------------------------------------
extern "C" void kernel_launch(void* const* d_in, const int* in_sizes, int n_in,
                              void* d_out, int out_size, void* d_ws, size_t ws_size,
                              hipStream_t stream) {
    const float* x      = (const float*)d_in[0];
    const float* conv_w = (const float*)d_in[1];
    const float* conv_b = (const float*)d_in[2];
    const float* dw_b   = (const float*)d_in[3];
    const float* fuse_w = (const float*)d_in[4];
    const float* fuse_b = (const float*)d_in[5];
    float* out = (float*)d_out;

    char* ws = (char*)d_ws;
    unsigned short* f_ws = (unsigned short*)ws;                       // 32 MiB
    float* g_ws          = (float*)(ws + 33554432);                   // 36 KiB
    unsigned short* cwpk = (unsigned short*)(ws + 33554432 + 36864);  // 32 KiB
    unsigned short* fwpk = (unsigned short*)(ws + 33554432 + 36864 + 32768);
    float* fbe           = (float*)(ws + 33554432 + 36864 + 32768 + 32768);

    k0_pack<<<dim3(64), dim3(256), 0, stream>>>(conv_w, fuse_w, fuse_b, dw_b, cwpk, fwpk, fbe);
    k1_conv<<<dim3(4096), dim3(256), 0, stream>>>(x, cwpk, conv_b, f_ws);
    k2_pool<<<dim3(1024), dim3(256), 0, stream>>>(f_ws, g_ws);
    k3_dwfuse<<<dim3(2048), dim3(512), 0, stream>>>(f_ws, g_ws, fwpk, fbe, out);
}

// Round 7
// 140.799 us; speedup vs baseline: 1.3311x; 1.3311x over previous
//
#include <hip/hip_runtime.h>
#include <hip/hip_bf16.h>

#define NB 16
#define C 256
#define C4 64
#define HDIM 128
#define WDIM 128
#define HW 16384

typedef __bf16 bf16x8 __attribute__((ext_vector_type(8)));
typedef float f32x4 __attribute__((ext_vector_type(4)));

__device__ __forceinline__ unsigned short f2bf(float x) {
    union { __bf16 h; unsigned short u; } c;
    c.h = (__bf16)x;                       // RNE
    return c.u;
}
__device__ __forceinline__ float bf2f(unsigned short b) {
    union { float f; unsigned u; } a; a.u = ((unsigned)b) << 16; return a.f;
}

// ---------------------------------------------------------------------------
// K0: pack conv_w (64x256) and fuse_w (256x64) into MFMA A-fragment order,
// and compute fuse_b_eff[c] = fuse_b[c] + sum_o fuse_w[c][o]*dw_b[o].
// A-fragment (16x16x32): lane = (m&15) | (((k>>3)&3)<<4), e = k&7.
// ---------------------------------------------------------------------------
__global__ __launch_bounds__(256) void k0_pack(
    const float* __restrict__ conv_w, const float* __restrict__ fuse_w,
    const float* __restrict__ fuse_b, const float* __restrict__ dw_b,
    unsigned short* __restrict__ cwpk, unsigned short* __restrict__ fwpk,
    float* __restrict__ fbe)
{
    int tid = blockIdx.x * 256 + threadIdx.x;   // 0..16383
    {   // conv_w: M=64, K=256
        int m = tid >> 8, k = tid & 255;
        int frag = (m >> 4) * 8 + (k >> 5);
        int lane = (m & 15) | (((k >> 3) & 3) << 4);
        int e = k & 7;
        cwpk[(frag * 64 + lane) * 8 + e] = f2bf(conv_w[m * 256 + k]);
    }
    {   // fuse_w: M=256, K=64
        int m = tid >> 6, k = tid & 63;
        int frag = (m >> 4) * 2 + (k >> 5);
        int lane = (m & 15) | (((k >> 3) & 3) << 4);
        int e = k & 7;
        fwpk[(frag * 64 + lane) * 8 + e] = f2bf(fuse_w[m * 64 + k]);
    }
    if (tid < 256) {
        float s = fuse_b[tid];
        #pragma unroll
        for (int o = 0; o < 64; ++o) s += fuse_w[tid * 64 + o] * dw_b[o];
        fbe[tid] = s;
    }
}

// ---------------------------------------------------------------------------
// K1: f = conv1(x) + conv_b  (GEMM: M=64 o-ch, N=128 px (one row), K=256 c).
// LDS-staged: per 32-ch K-chunk, x is loaded as f32x4 (512B-contiguous
// per channel-segment, nontemporal: x is single-use, keep it out of L2/LLC),
// converted to bf16, staged to LDS [32][138] (276B row stride: 4 gq groups
// hit distinct bank octants -> 2 lanes/bank, conflict-free), B-fragments
// assembled via 8x ds_read_u16. Next chunk's loads issue before MFMA phase.
// ---------------------------------------------------------------------------
__global__ __launch_bounds__(256) void k1_conv(
    const float* __restrict__ x, const unsigned short* __restrict__ cwpk,
    const float* __restrict__ conv_b, unsigned short* __restrict__ f_ws)
{
    __shared__ unsigned short xlds[32 * 138];     // 8832 B
    int blk = blockIdx.x;                         // 2048 = 16 n * 128 h
    int n = blk >> 7;
    int p0 = (blk & 127) * WDIM;                  // one image row
    int t = threadIdx.x;
    int lane = t & 63, wv = t >> 6, gq = lane >> 4, l15 = lane & 15;
    const float* xn = x + (size_t)n * C * HW + p0;

    int lch = t >> 5;                             // 0..7: channel-sub within chunk-j
    int lpx = (t & 31) * 4;                       // 0..124: pixel base (f32x4)

    f32x4 r[4];
    #pragma unroll
    for (int j = 0; j < 4; ++j)
        r[j] = __builtin_nontemporal_load(
            reinterpret_cast<const f32x4*>(&xn[(size_t)(j * 8 + lch) * HW + lpx]));

    f32x4 acc[2][4];
    #pragma unroll
    for (int pt = 0; pt < 2; ++pt)
        #pragma unroll
        for (int m = 0; m < 4; ++m) acc[pt][m] = (f32x4){0.f, 0.f, 0.f, 0.f};

    for (int kc = 0; kc < 8; ++kc) {
        // convert this chunk's registers to packed bf16
        unsigned int pk[4][2];
        #pragma unroll
        for (int j = 0; j < 4; ++j) {
            pk[j][0] = ((unsigned)f2bf(r[j].y) << 16) | f2bf(r[j].x);
            pk[j][1] = ((unsigned)f2bf(r[j].w) << 16) | f2bf(r[j].z);
        }
        __syncthreads();                          // prior chunk's frag reads done
        #pragma unroll
        for (int j = 0; j < 4; ++j) {
            unsigned int* dst = reinterpret_cast<unsigned int*>(
                &xlds[(j * 8 + lch) * 138 + lpx]);
            dst[0] = pk[j][0];
            dst[1] = pk[j][1];
        }
        __syncthreads();                          // tile visible to all waves
        if (kc < 7) {                             // prefetch next chunk early
            #pragma unroll
            for (int j = 0; j < 4; ++j)
                r[j] = __builtin_nontemporal_load(
                    reinterpret_cast<const f32x4*>(
                        &xn[(size_t)((kc + 1) * 32 + j * 8 + lch) * HW + lpx]));
        }
        bf16x8 a[4];
        #pragma unroll
        for (int m = 0; m < 4; ++m)
            a[m] = *reinterpret_cast<const bf16x8*>(cwpk + ((m * 8 + kc) * 64 + lane) * 8);
        #pragma unroll
        for (int pt = 0; pt < 2; ++pt) {
            int px = wv * 32 + pt * 16 + l15;
            union { bf16x8 v; unsigned short u[8]; } b;
            #pragma unroll
            for (int e = 0; e < 8; ++e)
                b.u[e] = xlds[(gq * 8 + e) * 138 + px];
            #pragma unroll
            for (int m = 0; m < 4; ++m)
                acc[pt][m] = __builtin_amdgcn_mfma_f32_16x16x32_bf16(a[m], b.v, acc[pt][m], 0, 0, 0);
        }
    }

    unsigned short* fn = f_ws + (size_t)n * C4 * HW;
    #pragma unroll
    for (int pt = 0; pt < 2; ++pt) {
        int px = p0 + wv * 32 + pt * 16 + l15;
        #pragma unroll
        for (int m = 0; m < 4; ++m) {
            #pragma unroll
            for (int e = 0; e < 4; ++e) {
                int o = m * 16 + gq * 4 + e;      // D row = 4*(lane>>4)+reg
                fn[(size_t)o * HW + px] = f2bf(acc[pt][m][e] + conv_b[o]);
            }
        }
    }
}

// ---------------------------------------------------------------------------
// K2: g[n,o,i,j] = mean of f over torch-adaptive bins.
// H=W=128, k=3: bins [0,43),[42,86),[85,128)  (row 42 & 85 in TWO bins).
// ---------------------------------------------------------------------------
__global__ __launch_bounds__(256) void k2_pool(
    const unsigned short* __restrict__ f_ws, float* __restrict__ g_ws)
{
    int no = blockIdx.x;                                  // 0..1023
    const unsigned short* fp = f_ws + (size_t)no * HW;
    int tid = threadIdx.x;
    float s[9];
    #pragma unroll
    for (int k = 0; k < 9; ++k) s[k] = 0.f;

    for (int it = 0; it < 8; ++it) {
        int p = (it * 256 + tid) * 8;                     // 8 bf16 per iter
        int h = p >> 7, wbase = p & 127;
        union { uint4 q; unsigned short u[8]; } d;
        d.q = *reinterpret_cast<const uint4*>(fp + p);
        float cs0 = 0.f, cs1 = 0.f, cs2 = 0.f;
        #pragma unroll
        for (int z = 0; z < 8; ++z) {
            float v = bf2f(d.u[z]);
            int w = wbase + z;
            if (w < 43)            cs0 += v;
            if (w >= 42 && w < 86) cs1 += v;
            if (w >= 85)           cs2 += v;
        }
        if (h < 43)            { s[0] += cs0; s[1] += cs1; s[2] += cs2; }
        if (h >= 42 && h < 86) { s[3] += cs0; s[4] += cs1; s[5] += cs2; }
        if (h >= 85)           { s[6] += cs0; s[7] += cs1; s[8] += cs2; }
    }

    __shared__ float red[4][9];
    int lane = tid & 63, wv = tid >> 6;
    #pragma unroll
    for (int k = 0; k < 9; ++k) {
        float v = s[k];
        for (int off = 32; off > 0; off >>= 1) v += __shfl_down(v, off, 64);
        s[k] = v;
    }
    if (lane == 0) {
        #pragma unroll
        for (int k = 0; k < 9; ++k) red[wv][k] = s[k];
    }
    __syncthreads();
    if (tid < 9) {
        const int cnt[3] = {43, 44, 43};
        float tot = red[0][tid] + red[1][tid] + red[2][tid] + red[3][tid];
        int i = tid / 3, j = tid - 3 * i;
        g_ws[no * 9 + tid] = tot / (float)(cnt[i] * cnt[j]);
    }
}

// ---------------------------------------------------------------------------
// K3: y = depthwise3x3(f, g) ; out = fuse_w . y + fuse_b_eff
// Block: one (n, row h), full 128 cols, 512 threads (8 waves).
// Plain stores (no NT): L2 merges the pj-adjacent 64B segments to full lines.
// ---------------------------------------------------------------------------
__global__ __launch_bounds__(512) void k3_dwfuse(
    const unsigned short* __restrict__ f_ws, const float* __restrict__ g_ws,
    const unsigned short* __restrict__ fwpk, const float* __restrict__ fbe,
    float* __restrict__ out)
{
    __shared__ unsigned short ylds[64][136];
    int blk = blockIdx.x;                 // 2048
    int n = blk >> 7;
    int h = blk & 127;
    int t = threadIdx.x;

    {   // depthwise: thread t -> channel o = t>>3, strip q = t&7 (16 px)
        int o = t >> 3, q = t & 7;
        int wb = q * 16;
        const unsigned short* fp = f_ws + (size_t)(n * 64 + o) * HW;
        const float* gp = g_ws + (n * 64 + o) * 9;
        float gv[9];
        #pragma unroll
        for (int k = 0; k < 9; ++k) gv[k] = gp[k];
        float y[16];
        #pragma unroll
        for (int i = 0; i < 16; ++i) y[i] = 0.f;
        #pragma unroll
        for (int dy = -1; dy <= 1; ++dy) {
            int hh = h + dy;
            if (hh < 0 || hh >= HDIM) continue;
            const unsigned short* row = fp + hh * WDIM;
            union { uint4 q4; unsigned short u[8]; } bA, bB;
            bA.q4 = *reinterpret_cast<const uint4*>(row + wb);
            bB.q4 = *reinterpret_cast<const uint4*>(row + wb + 8);
            float lft = bf2f(row[wb == 0 ? 0 : wb - 1]);
            if (wb == 0)   lft = 0.f;
            float rgt = bf2f(row[wb == 112 ? 127 : wb + 16]);
            if (wb == 112) rgt = 0.f;
            float rv[18];
            rv[0] = lft;
            #pragma unroll
            for (int z = 0; z < 8; ++z) rv[1 + z] = bf2f(bA.u[z]);
            #pragma unroll
            for (int z = 0; z < 8; ++z) rv[9 + z] = bf2f(bB.u[z]);
            rv[17] = rgt;
            float g0 = gv[(dy + 1) * 3], g1 = gv[(dy + 1) * 3 + 1], g2 = gv[(dy + 1) * 3 + 2];
            #pragma unroll
            for (int i = 0; i < 16; ++i)
                y[i] += g0 * rv[i] + g1 * rv[i + 1] + g2 * rv[i + 2];
        }
        union { uint4 q4[2]; unsigned short u[16]; } pk;
        #pragma unroll
        for (int i = 0; i < 16; ++i) pk.u[i] = f2bf(y[i]);
        *reinterpret_cast<uint4*>(&ylds[o][wb])     = pk.q4[0];
        *reinterpret_cast<uint4*>(&ylds[o][wb + 8]) = pk.q4[1];
    }
    __syncthreads();

    int lane = t & 63, wv = t >> 6, gq = lane >> 4;
    int chb = (wv & 3) * 64, pxb = (wv >> 2) * 64;
    f32x4 acc[4][4];
    #pragma unroll
    for (int a = 0; a < 4; ++a)
        #pragma unroll
        for (int b = 0; b < 4; ++b) acc[a][b] = (f32x4){0.f,0.f,0.f,0.f};

    #pragma unroll
    for (int kc = 0; kc < 2; ++kc) {
        bf16x8 bfr[4];
        #pragma unroll
        for (int pj = 0; pj < 4; ++pj) {
            union { bf16x8 v; unsigned short u[8]; } bb;
            #pragma unroll
            for (int e = 0; e < 8; ++e)
                bb.u[e] = ylds[kc * 32 + gq * 8 + e][pxb + pj * 16 + (lane & 15)];
            bfr[pj] = bb.v;
        }
        #pragma unroll
        for (int mc = 0; mc < 4; ++mc) {
            int mtile = (wv & 3) * 4 + mc;
            bf16x8 a = *reinterpret_cast<const bf16x8*>(
                fwpk + ((mtile * 2 + kc) * 64 + lane) * 8);
            #pragma unroll
            for (int pj = 0; pj < 4; ++pj)
                acc[mc][pj] = __builtin_amdgcn_mfma_f32_16x16x32_bf16(a, bfr[pj], acc[mc][pj], 0, 0, 0);
        }
    }

    size_t outbase = (size_t)n * C * HW + (size_t)h * WDIM;
    #pragma unroll
    for (int mc = 0; mc < 4; ++mc) {
        #pragma unroll
        for (int e = 0; e < 4; ++e) {
            int c = chb + mc * 16 + gq * 4 + e;
            float bias = fbe[c];
            #pragma unroll
            for (int pj = 0; pj < 4; ++pj) {
                int w = pxb + pj * 16 + (lane & 15);
                out[outbase + (size_t)c * HW + w] = acc[mc][pj][e] + bias;
            }
        }
    }
}

// ---------------------------------------------------------------------------
extern "C" void kernel_launch(void* const* d_in, const int* in_sizes, int n_in,
                              void* d_out, int out_size, void* d_ws, size_t ws_size,
                              hipStream_t stream) {
    const float* x      = (const float*)d_in[0];
    const float* conv_w = (const float*)d_in[1];
    const float* conv_b = (const float*)d_in[2];
    const float* dw_b   = (const float*)d_in[3];
    const float* fuse_w = (const float*)d_in[4];
    const float* fuse_b = (const float*)d_in[5];
    float* out = (float*)d_out;

    char* ws = (char*)d_ws;
    unsigned short* f_ws = (unsigned short*)ws;                       // 32 MiB
    float* g_ws          = (float*)(ws + 33554432);                   // 36 KiB
    unsigned short* cwpk = (unsigned short*)(ws + 33554432 + 36864);  // 32 KiB
    unsigned short* fwpk = (unsigned short*)(ws + 33554432 + 36864 + 32768);
    float* fbe           = (float*)(ws + 33554432 + 36864 + 32768 + 32768);

    k0_pack<<<dim3(64), dim3(256), 0, stream>>>(conv_w, fuse_w, fuse_b, dw_b, cwpk, fwpk, fbe);
    k1_conv<<<dim3(2048), dim3(256), 0, stream>>>(x, cwpk, conv_b, f_ws);
    k2_pool<<<dim3(1024), dim3(256), 0, stream>>>(f_ws, g_ws);
    k3_dwfuse<<<dim3(2048), dim3(512), 0, stream>>>(f_ws, g_ws, fwpk, fbe, out);
}